// Round 2
// baseline (196.515 us; speedup 1.0000x reference)
//
#include <hip/hip_runtime.h>
#include <hip/hip_bf16.h>

#define N_TOTAL 8192
#define B_HALF  4096
#define D       256
#define BM      128
#define BK      64
#define NTILES  (N_TOTAL / BM)            // 64
#define NBLK    (NTILES * (NTILES + 1) / 2)  // 2080

typedef __bf16 bf16x8v __attribute__((ext_vector_type(8)));
typedef float  f32x4v  __attribute__((ext_vector_type(4)));

__device__ __forceinline__ unsigned short f2bf(float x) {
    unsigned int u = __float_as_uint(x);
    unsigned int r = (u + 0x7FFFu + ((u >> 16) & 1u)) >> 16;
    return (unsigned short)r;
}
__device__ __forceinline__ float bf2f(unsigned short b) {
    return __uint_as_float(((unsigned int)b) << 16);
}

__device__ __forceinline__ void gload_lds16(const void* g, void* l) {
    __builtin_amdgcn_global_load_lds(
        (const __attribute__((address_space(1))) unsigned int*)g,
        (__attribute__((address_space(3))) unsigned int*)l,
        16, 0, 0);
}

// ---------------------------------------------------------------------------
// prep: f32 -> bf16 (ws), row norms sq[], col sums s[], sum(sq) (f64).
// Last block (ticket) computes the closed-form bandwidth:
//   sum(L2) = 2n*sum(sq) - 2*||colsum||^2 ; cexp = log2(e)/(16*bw)
// ---------------------------------------------------------------------------
__global__ void prep_kernel(const float* __restrict__ src,
                            const float* __restrict__ tgt,
                            unsigned short* __restrict__ tb,
                            float* __restrict__ sq,
                            float* __restrict__ s,
                            double* __restrict__ sumsq,
                            int* __restrict__ counter,
                            float* __restrict__ cexp) {
    __shared__ float colpart[4][256];
    __shared__ double dred[256];
    __shared__ int lastFlag;
    int tid = threadIdx.x;
    int wv = tid >> 6, ln = tid & 63;
    int row0 = blockIdx.x * 32 + wv * 8;

    float cp0 = 0.f, cp1 = 0.f, cp2 = 0.f, cp3 = 0.f;
    double dsum = 0.0;

    for (int t = 0; t < 8; ++t) {
        int row = row0 + t;
        const float* p = (row < B_HALF) ? (src + (size_t)row * D)
                                        : (tgt + (size_t)(row - B_HALF) * D);
        float4 v = *(const float4*)(p + ln * 4);
        unsigned short b0 = f2bf(v.x), b1 = f2bf(v.y), b2 = f2bf(v.z), b3 = f2bf(v.w);
        float x0 = bf2f(b0), x1 = bf2f(b1), x2 = bf2f(b2), x3 = bf2f(b3);
        ushort4 u; u.x = b0; u.y = b1; u.z = b2; u.w = b3;
        *(ushort4*)(tb + (size_t)row * D + ln * 4) = u;

        cp0 += x0; cp1 += x1; cp2 += x2; cp3 += x3;

        float sqp = x0 * x0 + x1 * x1 + x2 * x2 + x3 * x3;
        #pragma unroll
        for (int off = 32; off; off >>= 1) sqp += __shfl_down(sqp, off, 64);
        if (ln == 0) { sq[row] = sqp; dsum += (double)sqp; }
    }
    colpart[wv][ln * 4 + 0] = cp0;
    colpart[wv][ln * 4 + 1] = cp1;
    colpart[wv][ln * 4 + 2] = cp2;
    colpart[wv][ln * 4 + 3] = cp3;
    __syncthreads();
    float cs = colpart[0][tid] + colpart[1][tid] + colpart[2][tid] + colpart[3][tid];
    atomicAdd(&s[tid], cs);
    if (ln == 0) atomicAdd(sumsq, dsum);

    // last block computes cexp
    __threadfence();
    __syncthreads();
    if (tid == 0) lastFlag = (atomicAdd(counter, 1) == (int)gridDim.x - 1);
    __syncthreads();
    if (lastFlag) {
        __threadfence();
        float v = s[tid];
        dred[tid] = (double)v * (double)v;
        __syncthreads();
        for (int off = 128; off; off >>= 1) {
            if (tid < off) dred[tid] += dred[tid + off];
            __syncthreads();
        }
        if (tid == 0) {
            double sl2 = 2.0 * (double)N_TOTAL * sumsq[0] - 2.0 * dred[0];
            double bw = sl2 / ((double)N_TOTAL * N_TOTAL - (double)N_TOTAL);
            cexp[0] = (float)(1.4426950408889634 / (16.0 * bw));
        }
    }
}

// ---------------------------------------------------------------------------
// mmd: lower-triangular 128x128 Gram tiles via bf16 MFMA, fused
// L2 -> exp2 -> 5-kernel sum -> signed reduce. Per-block partial + last-block
// final reduction (no same-address f64 atomic storm).
// LDS tiles XOR-swizzled (T2, both-sides: pre-swizzled global source since
// global_load_lds writes linearly; same XOR on the ds_read side).
// Register-fragment prefetch lets the same LDS buffer be restaged for K-step
// t+1 while MFMAs of step t run on registers.
// ---------------------------------------------------------------------------
__device__ __forceinline__ void stage_tiles(const unsigned short* __restrict__ tb,
                                            int rowBase, int colBase, int kb0,
                                            int wv, int ln,
                                            unsigned short* ldsA,
                                            unsigned short* ldsB) {
    #pragma unroll
    for (int i = 0; i < 4; ++i) {
        int o = i * 4096 + wv * 1024 + ln * 16;          // linear LDS byte off
        int rowl = o >> 7;                               // BK*2 = 128 B/row
        int colb = (o & 127) ^ ((rowl & 7) << 4);        // pre-swizzled source
        const unsigned short* gA =
            tb + (size_t)(rowBase + rowl) * D + kb0 + (colb >> 1);
        gload_lds16(gA, (char*)ldsA + i * 4096 + wv * 1024);
        const unsigned short* gB =
            tb + (size_t)(colBase + rowl) * D + kb0 + (colb >> 1);
        gload_lds16(gB, (char*)ldsB + i * 4096 + wv * 1024);
    }
}

__global__ void mmd_kernel(const unsigned short* __restrict__ tb,
                           const float* __restrict__ sq,
                           const float* __restrict__ cexp_p,
                           double* __restrict__ partials,
                           int* __restrict__ counter,
                           float* __restrict__ out) {
    __shared__ __align__(16) unsigned short ldsA[BM * BK];  // 16 KB
    __shared__ __align__(16) unsigned short ldsB[BM * BK];  // 16 KB
    __shared__ float sqi[BM], sqj[BM];
    __shared__ float redbuf[4];
    __shared__ double dred[256];
    __shared__ int lastFlag;

    // triangle decode: block t -> (r,c), r >= c
    int t = blockIdx.x;
    int r = (int)((sqrtf(8.0f * (float)t + 1.0f) - 1.0f) * 0.5f);
    while ((r + 1) * (r + 2) / 2 <= t) ++r;
    while (r * (r + 1) / 2 > t) --r;
    int c = t - r * (r + 1) / 2;
    int rowBase = r * BM, colBase = c * BM;

    int tid = threadIdx.x;
    int wv = tid >> 6, ln = tid & 63;
    int wr = wv >> 1, wc = wv & 1;

    if (tid < BM) sqi[tid] = sq[rowBase + tid];
    else          sqj[tid - BM] = sq[colBase + (tid - BM)];
    float cexp = cexp_p[0];

    f32x4v acc[4][4] = {};

    stage_tiles(tb, rowBase, colBase, 0, wv, ln, ldsA, ldsB);

    for (int ks = 0; ks < D / BK; ++ks) {
        asm volatile("s_waitcnt vmcnt(0)" ::: "memory");
        __syncthreads();                       // staged tile visible to all

        // read ALL fragments of this K-step into registers (swizzled)
        bf16x8v a[2][4], b[2][4];
        #pragma unroll
        for (int kk = 0; kk < 2; ++kk) {
            #pragma unroll
            for (int mi = 0; mi < 4; ++mi) {
                int rowl = wr * 64 + mi * 16 + (ln & 15);
                int colb = (kk * 64 + (ln >> 4) * 16) ^ ((rowl & 7) << 4);
                a[kk][mi] = *(const bf16x8v*)((const char*)ldsA + rowl * 128 + colb);
            }
            #pragma unroll
            for (int ni = 0; ni < 4; ++ni) {
                int rowl = wc * 64 + ni * 16 + (ln & 15);
                int colb = (kk * 64 + (ln >> 4) * 16) ^ ((rowl & 7) << 4);
                b[kk][ni] = *(const bf16x8v*)((const char*)ldsB + rowl * 128 + colb);
            }
        }
        __syncthreads();                       // frags in regs; LDS is free

        if (ks < D / BK - 1)                   // restage under the MFMAs
            stage_tiles(tb, rowBase, colBase, (ks + 1) * BK, wv, ln, ldsA, ldsB);
        __builtin_amdgcn_sched_barrier(0);     // keep stage issue before MFMAs

        #pragma unroll
        for (int kk = 0; kk < 2; ++kk)
            #pragma unroll
            for (int mi = 0; mi < 4; ++mi)
                #pragma unroll
                for (int ni = 0; ni < 4; ++ni)
                    acc[mi][ni] = __builtin_amdgcn_mfma_f32_16x16x32_bf16(
                        a[kk][mi], b[kk][ni], acc[mi][ni], 0, 0, 0);
    }

    // epilogue: arg = (2*gram - (sq_i+sq_j)) * cexp ; kernels e0..e0^16
    // C/D layout (16x16x32): col = lane&15, row = (lane>>4)*4 + reg
    float tacc = 0.f;
    #pragma unroll
    for (int mi = 0; mi < 4; ++mi) {
        float si4[4];
        #pragma unroll
        for (int rg = 0; rg < 4; ++rg)
            si4[rg] = sqi[wr * 64 + mi * 16 + (ln >> 4) * 4 + rg];
        #pragma unroll
        for (int ni = 0; ni < 4; ++ni) {
            float sj = sqj[wc * 64 + ni * 16 + (ln & 15)];
            #pragma unroll
            for (int rg = 0; rg < 4; ++rg) {
                float arg = (2.0f * acc[mi][ni][rg] - (si4[rg] + sj)) * cexp;
                float e0 = __builtin_amdgcn_exp2f(arg);
                float e2 = e0 * e0, e4 = e2 * e2, e8 = e4 * e4, e16 = e8 * e8;
                tacc += (e0 + e2) + ((e4 + e8) + e16);
            }
        }
    }
    // tile-uniform sign (B_HALF is a multiple of BM) + triangle weight
    float w = ((r < B_HALF / BM) == (c < B_HALF / BM)) ? 1.f : -1.f;
    if (r != c) w *= 2.f;
    tacc *= w;

    #pragma unroll
    for (int off = 32; off; off >>= 1) tacc += __shfl_down(tacc, off, 64);
    if (ln == 0) redbuf[wv] = tacc;
    __syncthreads();

    if (tid == 0) {
        partials[blockIdx.x] =
            (double)(redbuf[0] + redbuf[1] + redbuf[2] + redbuf[3]);
        __threadfence();
        lastFlag = (atomicAdd(counter, 1) == (int)gridDim.x - 1);
    }
    __syncthreads();
    if (lastFlag) {                            // final reduction, fused
        __threadfence();
        double d = 0.0;
        for (int i = tid; i < NBLK; i += 256) d += partials[i];
        dred[tid] = d;
        __syncthreads();
        for (int off = 128; off; off >>= 1) {
            if (tid < off) dred[tid] += dred[tid + off];
            __syncthreads();
        }
        if (tid == 0)
            out[0] = (float)(dred[0] / (5.0 * (double)B_HALF * (double)B_HALF));
    }
}

// ---------------------------------------------------------------------------
extern "C" void kernel_launch(void* const* d_in, const int* in_sizes, int n_in,
                              void* d_out, int out_size, void* d_ws, size_t ws_size,
                              hipStream_t stream) {
    const float* src = (const float*)d_in[0];
    const float* tgt = (const float*)d_in[1];
    float* out = (float*)d_out;
    char* ws = (char*)d_ws;

    double* sumsq    = (double*)(ws + 0);
    int*    cntPrep  = (int*)(ws + 8);
    int*    cntMmd   = (int*)(ws + 12);
    float*  cexp     = (float*)(ws + 16);
    float*  s        = (float*)(ws + 64);      // 256 f32
    float*  sq       = (float*)(ws + 4096);    // 8192 f32
    double* partials = (double*)(ws + 40960);  // 2080 f64
    unsigned short* tb = (unsigned short*)(ws + 65536);  // 8192*256 bf16 = 4 MB

    // zero accumulators/counters (ws poisoned 0xAA, not re-poisoned per replay)
    hipMemsetAsync(ws, 0, 2048, stream);

    prep_kernel<<<N_TOTAL / 32, 256, 0, stream>>>(src, tgt, tb, sq, s, sumsq,
                                                  cntPrep, cexp);
    mmd_kernel<<<NBLK, 256, 0, stream>>>(tb, sq, cexp, partials, cntMmd, out);
}

// Round 3
// 104.434 us; speedup vs baseline: 1.8817x; 1.8817x over previous
//
#include <hip/hip_runtime.h>
#include <hip/hip_bf16.h>

#define N_TOTAL 8192
#define B_HALF  4096
#define D       256
#define BM      128
#define BK      64
#define NTILES  (N_TOTAL / BM)               // 64
#define NBLK    (NTILES * (NTILES + 1) / 2)  // 2080

typedef __bf16 bf16x8v __attribute__((ext_vector_type(8)));
typedef float  f32x4v  __attribute__((ext_vector_type(4)));

__device__ __forceinline__ unsigned short f2bf(float x) {
    unsigned int u = __float_as_uint(x);
    return (unsigned short)((u + 0x7FFFu + ((u >> 16) & 1u)) >> 16);
}
__device__ __forceinline__ float bf2f(unsigned short b) {
    return __uint_as_float(((unsigned int)b) << 16);
}

__device__ __forceinline__ void gload_lds16(const void* g, void* l) {
    __builtin_amdgcn_global_load_lds(
        (const __attribute__((address_space(1))) unsigned int*)g,
        (__attribute__((address_space(3))) unsigned int*)l,
        16, 0, 0);
}

// ---------------------------------------------------------------------------
// prep: f32 -> bf16 (ws), row norms sq[], col sums s[] (f32 HW atomics,
// distinct addresses), per-block f64 sum(sq) partial (NO same-address f64
// CAS atomics). Last block computes closed-form bandwidth:
//   sum(L2) = 2n*sum(sq) - 2*||colsum||^2 ; cexp = log2(e)/(16*bw)
// ---------------------------------------------------------------------------
__global__ void prep_kernel(const float* __restrict__ src,
                            const float* __restrict__ tgt,
                            unsigned short* __restrict__ tb,
                            float* __restrict__ sq,
                            float* __restrict__ s,
                            double* __restrict__ sumsq_part,
                            int* __restrict__ counter,
                            float* __restrict__ cexp) {
    __shared__ float colpart[4][256];
    __shared__ double wsum[4];
    __shared__ double red1[256], red2[256];
    __shared__ int lastFlag;
    int tid = threadIdx.x;
    int wv = tid >> 6, ln = tid & 63;
    int row0 = blockIdx.x * 32 + wv * 8;

    float cp0 = 0.f, cp1 = 0.f, cp2 = 0.f, cp3 = 0.f;
    double dsum = 0.0;

    for (int t = 0; t < 8; ++t) {
        int row = row0 + t;
        const float* p = (row < B_HALF) ? (src + (size_t)row * D)
                                        : (tgt + (size_t)(row - B_HALF) * D);
        float4 v = *(const float4*)(p + ln * 4);
        unsigned short b0 = f2bf(v.x), b1 = f2bf(v.y), b2 = f2bf(v.z), b3 = f2bf(v.w);
        float x0 = bf2f(b0), x1 = bf2f(b1), x2 = bf2f(b2), x3 = bf2f(b3);
        ushort4 u; u.x = b0; u.y = b1; u.z = b2; u.w = b3;
        *(ushort4*)(tb + (size_t)row * D + ln * 4) = u;

        cp0 += x0; cp1 += x1; cp2 += x2; cp3 += x3;

        float sqp = x0 * x0 + x1 * x1 + x2 * x2 + x3 * x3;
        #pragma unroll
        for (int off = 32; off; off >>= 1) sqp += __shfl_down(sqp, off, 64);
        if (ln == 0) { sq[row] = sqp; dsum += (double)sqp; }
    }
    colpart[wv][ln * 4 + 0] = cp0;
    colpart[wv][ln * 4 + 1] = cp1;
    colpart[wv][ln * 4 + 2] = cp2;
    colpart[wv][ln * 4 + 3] = cp3;
    if (ln == 0) wsum[wv] = dsum;
    __syncthreads();
    float cs = colpart[0][tid] + colpart[1][tid] + colpart[2][tid] + colpart[3][tid];
    atomicAdd(&s[tid], cs);
    if (tid == 0)
        sumsq_part[blockIdx.x] = wsum[0] + wsum[1] + wsum[2] + wsum[3];

    __threadfence();
    __syncthreads();
    if (tid == 0) lastFlag = (atomicAdd(counter, 1) == (int)gridDim.x - 1);
    __syncthreads();
    if (lastFlag) {
        __threadfence();
        float v = s[tid];
        red1[tid] = sumsq_part[tid];             // 256 blocks
        red2[tid] = (double)v * (double)v;
        __syncthreads();
        for (int off = 128; off; off >>= 1) {
            if (tid < off) { red1[tid] += red1[tid + off]; red2[tid] += red2[tid + off]; }
            __syncthreads();
        }
        if (tid == 0) {
            double sl2 = 2.0 * (double)N_TOTAL * red1[0] - 2.0 * red2[0];
            double bw = sl2 / ((double)N_TOTAL * N_TOTAL - (double)N_TOTAL);
            cexp[0] = (float)(1.4426950408889634 / (16.0 * bw));
        }
    }
}

// ---------------------------------------------------------------------------
// mmd: lower-triangular 128x128 Gram tiles, bf16 MFMA, fused exp epilogue.
// - XOR-swizzled LDS (both-sides: pre-swizzled global source since
//   global_load_lds writes linearly; same XOR on ds_read) -> 0 bank conflicts
// - double-buffered LDS with COUNTED vmcnt + raw s_barrier (no __syncthreads
//   in the K-loop: it would drain vmcnt(0) and serialize the pipeline)
// - fragments scoped per-kk (a[4],b[4] = 32 VGPRs live) -> no spills
// ---------------------------------------------------------------------------
__device__ __forceinline__ void stage_tiles(const unsigned short* __restrict__ tb,
                                            int rowBase, int colBase, int kb0,
                                            int wv, int ln,
                                            unsigned short* ldsA,
                                            unsigned short* ldsB) {
    #pragma unroll
    for (int i = 0; i < 4; ++i) {
        int o = i * 4096 + wv * 1024 + ln * 16;          // linear LDS byte off
        int rowl = o >> 7;                               // 128 B per row
        int colb = (o & 127) ^ ((rowl & 7) << 4);        // pre-swizzled source
        gload_lds16(tb + (size_t)(rowBase + rowl) * D + kb0 + (colb >> 1),
                    (char*)ldsA + i * 4096 + wv * 1024);
        gload_lds16(tb + (size_t)(colBase + rowl) * D + kb0 + (colb >> 1),
                    (char*)ldsB + i * 4096 + wv * 1024);
    }
}

__global__ __launch_bounds__(256, 2)
void mmd_kernel(const unsigned short* __restrict__ tb,
                const float* __restrict__ sq,
                const float* __restrict__ cexp_p,
                double* __restrict__ partials,
                int* __restrict__ counter,
                float* __restrict__ out) {
    __shared__ __align__(16) unsigned short ldsA[2][BM * BK];  // 32 KB
    __shared__ __align__(16) unsigned short ldsB[2][BM * BK];  // 32 KB
    __shared__ float sqi[BM], sqj[BM];
    __shared__ float redbuf[4];
    __shared__ double dred[256];
    __shared__ int lastFlag;

    // triangle decode: block t -> (r,c), r >= c
    int t = blockIdx.x;
    int r = (int)((sqrtf(8.0f * (float)t + 1.0f) - 1.0f) * 0.5f);
    while ((r + 1) * (r + 2) / 2 <= t) ++r;
    while (r * (r + 1) / 2 > t) --r;
    int c = t - r * (r + 1) / 2;
    int rowBase = r * BM, colBase = c * BM;

    int tid = threadIdx.x;
    int wv = tid >> 6, ln = tid & 63;
    int wr = wv >> 1, wc = wv & 1;

    // prologue: start both buffers' staging, overlap scalar/LDS prologue
    stage_tiles(tb, rowBase, colBase, 0, wv, ln, ldsA[0], ldsB[0]);
    stage_tiles(tb, rowBase, colBase, BK, wv, ln, ldsA[1], ldsB[1]);

    if (tid < BM) sqi[tid] = sq[rowBase + tid];
    else          sqj[tid - BM] = sq[colBase + (tid - BM)];
    float cexp = cexp_p[0];

    f32x4v acc[4][4] = {};

    asm volatile("s_waitcnt vmcnt(8)" ::: "memory");   // buf0 landed
    __builtin_amdgcn_s_barrier();

    #pragma unroll
    for (int ks = 0; ks < 4; ++ks) {
        const int cur = ks & 1;
        const unsigned short* lA = ldsA[cur];
        const unsigned short* lB = ldsB[cur];

        #pragma unroll
        for (int kk = 0; kk < 2; ++kk) {
            bf16x8v a[4], b[4];
            #pragma unroll
            for (int mi = 0; mi < 4; ++mi) {
                int rowl = wr * 64 + mi * 16 + (ln & 15);
                int colb = (kk * 64 + (ln >> 4) * 16) ^ ((rowl & 7) << 4);
                a[mi] = *(const bf16x8v*)((const char*)lA + rowl * 128 + colb);
            }
            #pragma unroll
            for (int ni = 0; ni < 4; ++ni) {
                int rowl = wc * 64 + ni * 16 + (ln & 15);
                int colb = (kk * 64 + (ln >> 4) * 16) ^ ((rowl & 7) << 4);
                b[ni] = *(const bf16x8v*)((const char*)lB + rowl * 128 + colb);
            }
            #pragma unroll
            for (int mi = 0; mi < 4; ++mi)
                #pragma unroll
                for (int ni = 0; ni < 4; ++ni)
                    acc[mi][ni] = __builtin_amdgcn_mfma_f32_16x16x32_bf16(
                        a[mi], b[ni], acc[mi][ni], 0, 0, 0);
        }

        // all waves done reading lds[cur] (frag reads drained by the
        // compiler's lgkmcnt before their MFMA uses)
        asm volatile("" ::: "memory");
        __builtin_amdgcn_s_barrier();

        if (ks + 2 < 4)   // restage the buffer we just finished reading
            stage_tiles(tb, rowBase, colBase, (ks + 2) * BK, wv, ln,
                        ldsA[cur], ldsB[cur]);

        if (ks < 3) {     // make buf[ks+1] ready; keep newest stage in flight
            if (ks + 2 < 4) asm volatile("s_waitcnt vmcnt(8)" ::: "memory");
            else            asm volatile("s_waitcnt vmcnt(0)" ::: "memory");
            __builtin_amdgcn_s_barrier();
        }
    }

    // epilogue: arg = (2*gram - (sq_i+sq_j)) * cexp ; kernels e0..e0^16
    // C/D layout (16x16x32): col = lane&15, row = (lane>>4)*4 + reg
    float tacc = 0.f;
    #pragma unroll
    for (int mi = 0; mi < 4; ++mi) {
        float si4[4];
        #pragma unroll
        for (int rg = 0; rg < 4; ++rg)
            si4[rg] = sqi[wr * 64 + mi * 16 + (ln >> 4) * 4 + rg];
        #pragma unroll
        for (int ni = 0; ni < 4; ++ni) {
            float sj = sqj[wc * 64 + ni * 16 + (ln & 15)];
            #pragma unroll
            for (int rg = 0; rg < 4; ++rg) {
                float arg = (2.0f * acc[mi][ni][rg] - (si4[rg] + sj)) * cexp;
                float e0 = __builtin_amdgcn_exp2f(arg);
                float e2 = e0 * e0, e4 = e2 * e2, e8 = e4 * e4, e16 = e8 * e8;
                tacc += (e0 + e2) + ((e4 + e8) + e16);
            }
        }
    }
    // tile-uniform sign (B_HALF is a multiple of BM) + triangle weight
    float w = ((r < B_HALF / BM) == (c < B_HALF / BM)) ? 1.f : -1.f;
    if (r != c) w *= 2.f;
    tacc *= w;

    #pragma unroll
    for (int off = 32; off; off >>= 1) tacc += __shfl_down(tacc, off, 64);
    if (ln == 0) redbuf[wv] = tacc;
    __syncthreads();

    if (tid == 0) {
        partials[blockIdx.x] =
            (double)(redbuf[0] + redbuf[1] + redbuf[2] + redbuf[3]);
        __threadfence();
        lastFlag = (atomicAdd(counter, 1) == (int)gridDim.x - 1);
    }
    __syncthreads();
    if (lastFlag) {
        __threadfence();
        double d = 0.0;
        for (int i = tid; i < NBLK; i += 256) d += partials[i];
        dred[tid] = d;
        __syncthreads();
        for (int off = 128; off; off >>= 1) {
            if (tid < off) dred[tid] += dred[tid + off];
            __syncthreads();
        }
        if (tid == 0)
            out[0] = (float)(dred[0] / (5.0 * (double)B_HALF * (double)B_HALF));
    }
}

// ---------------------------------------------------------------------------
extern "C" void kernel_launch(void* const* d_in, const int* in_sizes, int n_in,
                              void* d_out, int out_size, void* d_ws, size_t ws_size,
                              hipStream_t stream) {
    const float* src = (const float*)d_in[0];
    const float* tgt = (const float*)d_in[1];
    float* out = (float*)d_out;
    char* ws = (char*)d_ws;

    int*    cntPrep  = (int*)(ws + 0);
    int*    cntMmd   = (int*)(ws + 8);
    float*  cexp     = (float*)(ws + 16);
    float*  s        = (float*)(ws + 64);      // 256 f32, atomic-accumulated
    double* ssqpart  = (double*)(ws + 2048);   // 256 f64, fully overwritten
    float*  sq       = (float*)(ws + 4096);    // 8192 f32
    double* partials = (double*)(ws + 40960);  // 2080 f64, fully overwritten
    unsigned short* tb = (unsigned short*)(ws + 65536);  // 4 MB bf16

    // zero counters + s[] (ws poisoned 0xAA; not re-poisoned between replays)
    hipMemsetAsync(ws, 0, 2048, stream);

    prep_kernel<<<N_TOTAL / 32, 256, 0, stream>>>(src, tgt, tb, sq, s,
                                                  ssqpart, cntPrep, cexp);
    mmd_kernel<<<NBLK, 256, 0, stream>>>(tb, sq, cexp, partials, cntMmd, out);
}